// Round 12
// baseline (88.112 us; speedup 1.0000x reference)
//
#include <hip/hip_runtime.h>
#include <hip/hip_fp16.h>
#include <math.h>

// GATv2Conv forward. fp16 xl/xr; padded-bucket CSR (u32 binned, u16 csr);
// merged MFMA proj; aggregate: 16 thr/node, 8 ch/lane packed-fp16, unroll x4.

#define NN 50000
#define NE 800000
#define NHEADS 8
#define CH 16
#define FDIM 128
#define NEG_SLOPE 0.2f

#define BSHIFT 8
#define NBUCK ((NN + 255) >> 8)           // 196 coarse buckets (dst>>8)
#define BCAP 5120                          // mean 4082, sigma 64 -> 16 sigma
#define CHUNK 4096
#define NCHUNK ((NE + CHUNK - 1) / CHUNK)  // 196

typedef _Float16 half8 __attribute__((ext_vector_type(8)));
typedef _Float16 h2v  __attribute__((ext_vector_type(2)));
typedef float f32x4 __attribute__((ext_vector_type(4)));

// ---------------- projection GEMM via MFMA (merged Wl+Wr) ----------------
#define PBM 64
#define PTILES ((NN + PBM - 1) / PBM)   // 782

__global__ __launch_bounds__(512) void gat_proj_mfma(
        const float* __restrict__ x,
        const float* __restrict__ Wl,
        const float* __restrict__ Wr,
        __half* __restrict__ xl,
        __half* __restrict__ xr) {
    __shared__ __half Al[PBM][FDIM];    // 16 KB, 16B-chunk XOR-swizzled
    __shared__ __half Bl[256][FDIM];    // 64 KB, rows 0..127 Wl, 128..255 Wr

    const int t    = threadIdx.x;
    const int lane = t & 63;
    const int wave = t >> 6;            // 0..7
    const int wm   = wave >> 2;         // 0..1
    const int wn   = wave & 3;          // 0..3
    const int lr   = lane & 15;
    const int lh   = lane >> 4;

    const int row0 = blockIdx.x * PBM;

    #pragma unroll
    for (int i = 0; i < 2; ++i) {
        int c   = t + i * 512;
        int row = c >> 4;
        int c16 = c & 15;
        int sc  = c16 ^ (row & 7);
        int arow = row0 + row;
        if (arow >= NN) arow = NN - 1;
        const float4* src = reinterpret_cast<const float4*>(
            x + (size_t)arow * FDIM + c16 * 8);
        float4 v0 = src[0];
        float4 v1 = src[1];
        union { uint4 u; __half2 h[4]; } pk;
        pk.h[0] = __floats2half2_rn(v0.x, v0.y);
        pk.h[1] = __floats2half2_rn(v0.z, v0.w);
        pk.h[2] = __floats2half2_rn(v1.x, v1.y);
        pk.h[3] = __floats2half2_rn(v1.z, v1.w);
        *reinterpret_cast<uint4*>(&Al[row][sc * 8]) = pk.u;
    }
    #pragma unroll
    for (int i = 0; i < 8; ++i) {
        int c   = t + i * 512;
        int row = c >> 4;               // 0..255
        int c16 = c & 15;
        int sc  = c16 ^ (row & 7);
        const float* wr = (row < 128) ? (Wl + (size_t)row * FDIM)
                                      : (Wr + (size_t)(row - 128) * FDIM);
        const float4* src = reinterpret_cast<const float4*>(wr + c16 * 8);
        float4 v0 = src[0];
        float4 v1 = src[1];
        union { uint4 u; __half2 h[4]; } pk;
        pk.h[0] = __floats2half2_rn(v0.x, v0.y);
        pk.h[1] = __floats2half2_rn(v0.z, v0.w);
        pk.h[2] = __floats2half2_rn(v1.x, v1.y);
        pk.h[3] = __floats2half2_rn(v1.z, v1.w);
        *reinterpret_cast<uint4*>(&Bl[row][sc * 8]) = pk.u;
    }
    __syncthreads();

    f32x4 acc[2][4] = {};
    const char* Ab = reinterpret_cast<const char*>(&Al[0][0]);
    const char* Bb = reinterpret_cast<const char*>(&Bl[0][0]);

    #pragma unroll
    for (int kc = 0; kc < 4; ++kc) {
        half8 a[2], b[4];
        #pragma unroll
        for (int mi = 0; mi < 2; ++mi) {
            int row = wm * 32 + mi * 16 + lr;
            int bc  = (kc * 64 + 16 * lh) ^ ((row & 7) << 4);
            a[mi] = *reinterpret_cast<const half8*>(Ab + row * 256 + bc);
        }
        #pragma unroll
        for (int ni = 0; ni < 4; ++ni) {
            int row = wn * 64 + ni * 16 + lr;
            int bc  = (kc * 64 + 16 * lh) ^ ((row & 7) << 4);
            b[ni] = *reinterpret_cast<const half8*>(Bb + row * 256 + bc);
        }
        #pragma unroll
        for (int mi = 0; mi < 2; ++mi)
            #pragma unroll
            for (int ni = 0; ni < 4; ++ni)
                acc[mi][ni] = __builtin_amdgcn_mfma_f32_16x16x32_f16(
                    a[mi], b[ni], acc[mi][ni], 0, 0, 0);
    }

    #pragma unroll
    for (int mi = 0; mi < 2; ++mi) {
        #pragma unroll
        for (int ni = 0; ni < 4; ++ni) {
            int gc = wn * 64 + ni * 16 + lr;
            __half* outp = (gc < 128) ? xl : xr;
            int col = gc & 127;
            #pragma unroll
            for (int r = 0; r < 4; ++r) {
                int grow = row0 + wm * 32 + mi * 16 + 4 * lh + r;
                if (grow < NN)
                    outp[(size_t)grow * FDIM + col] = __float2half(acc[mi][ni][r]);
            }
        }
    }
}

// ---------------- CSR build: padded buckets, packed u32/u16 --------------
__global__ void gat_init_cursor(int* __restrict__ bcursor) {
    int t = threadIdx.x;
    if (t < NBUCK) bcursor[t] = t * BCAP;
}

// entry = (src << 8) | (dst & 255); src < 65536 so fits 24 bits
__global__ __launch_bounds__(256) void gat_bin_pass(
        const int* __restrict__ ei,
        int* __restrict__ bcursor,
        unsigned* __restrict__ binned) {
    __shared__ int hist[NBUCK];
    __shared__ int base_l[NBUCK];
    int t = threadIdx.x;
    for (int i = t; i < NBUCK; i += 256) hist[i] = 0;
    __syncthreads();

    int cbase = blockIdx.x * CHUNK;
    int s[CHUNK / 256], d[CHUNK / 256], r[CHUNK / 256];
    #pragma unroll
    for (int i = 0; i < CHUNK / 256; ++i) {
        int m = cbase + i * 256 + t;
        if (m < NE) {
            s[i] = ei[m];
            d[i] = ei[NE + m];
            r[i] = atomicAdd(&hist[d[i] >> BSHIFT], 1);
        } else {
            d[i] = -1;
        }
    }
    __syncthreads();
    for (int i = t; i < NBUCK; i += 256)
        base_l[i] = hist[i] ? atomicAdd(&bcursor[i], hist[i]) : 0;
    __syncthreads();
    #pragma unroll
    for (int i = 0; i < CHUNK / 256; ++i) {
        if (d[i] >= 0) {
            int pos = base_l[d[i] >> BSHIFT] + r[i];
            binned[pos] = ((unsigned)s[i] << 8) | (unsigned)(d[i] & 255);
        }
    }
}

// per-bucket fine sort from LDS-cached bucket; csr as u16
__global__ __launch_bounds__(256) void gat_fine_pass(
        const unsigned* __restrict__ binned,
        const int* __restrict__ bcursor,
        int* __restrict__ rowstart,
        int* __restrict__ rowend,
        unsigned short* __restrict__ csr16) {
    __shared__ unsigned ebuf[BCAP];     // 20 KB
    __shared__ int cnt_c[256];
    __shared__ int sbuf[256];
    __shared__ int cur_c[256];
    int t = threadIdx.x;
    int b = blockIdx.x;
    int base = b * BCAP;
    int cnt  = bcursor[b] - base;

    for (int j = t; j < cnt; j += 256) ebuf[j] = binned[base + j];
    cnt_c[t] = 0;
    __syncthreads();
    for (int j = t; j < cnt; j += 256)
        atomicAdd(&cnt_c[ebuf[j] & 255u], 1);
    __syncthreads();

    int v = cnt_c[t];
    sbuf[t] = v;
    __syncthreads();
    for (int off = 1; off < 256; off <<= 1) {
        int add = (t >= off) ? sbuf[t - off] : 0;
        __syncthreads();
        sbuf[t] += add;
        __syncthreads();
    }
    int excl = sbuf[t] - v;
    cur_c[t] = excl;
    int node = (b << BSHIFT) + t;
    if (node < NN) {
        rowstart[node] = base + excl;
        rowend[node]   = base + excl + v;
    }
    __syncthreads();

    for (int j = t; j < cnt; j += 256) {
        unsigned e = ebuf[j];
        int pos = atomicAdd(&cur_c[e & 255u], 1);
        csr16[base + pos] = (unsigned short)(e >> 8);
    }
}

// ---------------- fused aggregate: 16 thr/node, 8 ch/lane ----------------
// leaky(s) = 0.6*s + 0.4*|s|  (exact for slope 0.2)
__device__ __forceinline__ float gat_dot8_h(const h2v e[4], const h2v at[4]) {
#if __has_builtin(__builtin_amdgcn_fdot2)
    float p = __builtin_amdgcn_fdot2(e[0], at[0], 0.0f, false);
    p = __builtin_amdgcn_fdot2(e[1], at[1], p, false);
    p = __builtin_amdgcn_fdot2(e[2], at[2], p, false);
    return __builtin_amdgcn_fdot2(e[3], at[3], p, false);
#else
    float p = 0.f;
    for (int q = 0; q < 4; ++q)
        p += (float)e[q][0] * (float)at[q][0] + (float)e[q][1] * (float)at[q][1];
    return p;
#endif
}

__device__ __forceinline__ void gat_edge_step8(
        const h2v xi[4], const h2v at[4], uint4 raw,
        float4& accA, float4& accB, float& den) {
    union uh { unsigned u; h2v v; };
    uh j[4];
    j[0].u = raw.x; j[1].u = raw.y; j[2].u = raw.z; j[3].u = raw.w;
    const h2v c1 = {(_Float16)0.6f, (_Float16)0.6f};
    const h2v c2 = {(_Float16)0.4f, (_Float16)0.4f};
    h2v e[4];
    #pragma unroll
    for (int q = 0; q < 4; ++q) {
        h2v s = xi[q] + j[q].v;
        uh bb, aa;
        bb.v = s;
        aa.u = bb.u & 0x7FFF7FFFu;
        e[q] = s * c1 + aa.v * c2;
    }
    float p = gat_dot8_h(e, at);
    p += __shfl_xor(p, 1);
    float ea = __expf(p);
    accA.x = fmaf((float)j[0].v[0], ea, accA.x);
    accA.y = fmaf((float)j[0].v[1], ea, accA.y);
    accA.z = fmaf((float)j[1].v[0], ea, accA.z);
    accA.w = fmaf((float)j[1].v[1], ea, accA.w);
    accB.x = fmaf((float)j[2].v[0], ea, accB.x);
    accB.y = fmaf((float)j[2].v[1], ea, accB.y);
    accB.z = fmaf((float)j[3].v[0], ea, accB.z);
    accB.w = fmaf((float)j[3].v[1], ea, accB.w);
    den += ea;
}

__global__ __launch_bounds__(256) void gat_aggregate_kernel(
        const __half* __restrict__ xl,
        const __half* __restrict__ xr,
        const float* __restrict__ att,
        const float* __restrict__ bias,
        const int* __restrict__ rowstart,
        const int* __restrict__ rowend,
        const unsigned short* __restrict__ csr16,
        float* __restrict__ out) {
    int node = blockIdx.x * 16 + (threadIdx.x >> 4);
    int u = threadIdx.x & 15;              // lane group: 8 channels u*8..u*8+7
    if (node >= NN) return;

    uint4 xiraw = *reinterpret_cast<const uint4*>(xr + (size_t)node * FDIM + u * 8);
    union uh { unsigned u; h2v v; };
    h2v xi[4];
    { uh w; w.u = xiraw.x; xi[0] = w.v; w.u = xiraw.y; xi[1] = w.v;
      w.u = xiraw.z; xi[2] = w.v; w.u = xiraw.w; xi[3] = w.v; }
    const float4 atf0 = *reinterpret_cast<const float4*>(att + u * 8);
    const float4 atf1 = *reinterpret_cast<const float4*>(att + u * 8 + 4);
    h2v at[4];
    at[0] = (h2v){(_Float16)atf0.x, (_Float16)atf0.y};
    at[1] = (h2v){(_Float16)atf0.z, (_Float16)atf0.w};
    at[2] = (h2v){(_Float16)atf1.x, (_Float16)atf1.y};
    at[3] = (h2v){(_Float16)atf1.z, (_Float16)atf1.w};
    const float4 bi0 = *reinterpret_cast<const float4*>(bias + u * 8);
    const float4 bi1 = *reinterpret_cast<const float4*>(bias + u * 8 + 4);
    int e0 = rowstart[node];
    int e1 = rowend[node];

    float4 aA0 = {0,0,0,0}, aB0 = {0,0,0,0};
    float4 aA1 = {0,0,0,0}, aB1 = {0,0,0,0};
    float4 aA2 = {0,0,0,0}, aB2 = {0,0,0,0};
    float4 aA3 = {0,0,0,0}, aB3 = {0,0,0,0};
    float den0 = 0.f, den1 = 0.f, den2 = 0.f, den3 = 0.f;

    int e = e0;
    for (; e + 4 <= e1; e += 4) {
        int s0 = csr16[e + 0];
        int s1 = csr16[e + 1];
        int s2 = csr16[e + 2];
        int s3 = csr16[e + 3];
        uint4 r0 = *reinterpret_cast<const uint4*>(xl + (size_t)s0 * FDIM + u * 8);
        uint4 r1 = *reinterpret_cast<const uint4*>(xl + (size_t)s1 * FDIM + u * 8);
        uint4 r2 = *reinterpret_cast<const uint4*>(xl + (size_t)s2 * FDIM + u * 8);
        uint4 r3 = *reinterpret_cast<const uint4*>(xl + (size_t)s3 * FDIM + u * 8);
        gat_edge_step8(xi, at, r0, aA0, aB0, den0);
        gat_edge_step8(xi, at, r1, aA1, aB1, den1);
        gat_edge_step8(xi, at, r2, aA2, aB2, den2);
        gat_edge_step8(xi, at, r3, aA3, aB3, den3);
    }
    for (; e < e1; ++e) {
        int s0 = csr16[e];
        uint4 r0 = *reinterpret_cast<const uint4*>(xl + (size_t)s0 * FDIM + u * 8);
        gat_edge_step8(xi, at, r0, aA0, aB0, den0);
    }

    float4 accA, accB;
    accA.x = (aA0.x + aA1.x) + (aA2.x + aA3.x);
    accA.y = (aA0.y + aA1.y) + (aA2.y + aA3.y);
    accA.z = (aA0.z + aA1.z) + (aA2.z + aA3.z);
    accA.w = (aA0.w + aA1.w) + (aA2.w + aA3.w);
    accB.x = (aB0.x + aB1.x) + (aB2.x + aB3.x);
    accB.y = (aB0.y + aB1.y) + (aB2.y + aB3.y);
    accB.z = (aB0.z + aB1.z) + (aB2.z + aB3.z);
    accB.w = (aB0.w + aB1.w) + (aB2.w + aB3.w);
    float den = (den0 + den1) + (den2 + den3);

    float inv = 1.0f / (den + 1e-16f);
    float4 o0, o1;
    o0.x = accA.x * inv + bi0.x;
    o0.y = accA.y * inv + bi0.y;
    o0.z = accA.z * inv + bi0.z;
    o0.w = accA.w * inv + bi0.w;
    o1.x = accB.x * inv + bi1.x;
    o1.y = accB.y * inv + bi1.y;
    o1.z = accB.z * inv + bi1.z;
    o1.w = accB.w * inv + bi1.w;
    float* op = out + (size_t)node * FDIM + u * 8;
    *reinterpret_cast<float4*>(op)     = o0;
    *reinterpret_cast<float4*>(op + 4) = o1;
}

extern "C" void kernel_launch(void* const* d_in, const int* in_sizes, int n_in,
                              void* d_out, int out_size, void* d_ws, size_t ws_size,
                              hipStream_t stream) {
    const float* x    = (const float*)d_in[0];
    const int*   ei   = (const int*)d_in[1];
    const float* Wl   = (const float*)d_in[2];
    const float* Wr   = (const float*)d_in[3];
    const float* att  = (const float*)d_in[4];
    const float* bias = (const float*)d_in[5];
    float* out = (float*)d_out;

    // ws layout (d_ws 256-aligned)
    __half* xl = (__half*)d_ws;                        // 12.8 MB
    __half* xr = xl + (size_t)NN * FDIM;               // 12.8 MB
    unsigned* binned = (unsigned*)(xr + (size_t)NN * FDIM); // NBUCK*BCAP u32 (4 MB)
    unsigned short* csr16 = (unsigned short*)(binned + (size_t)NBUCK * BCAP); // 2 MB
    int* rowstart  = (int*)(csr16 + (size_t)NBUCK * BCAP); // NN
    int* rowend    = rowstart + NN + 8;                // NN
    int* bcursor   = rowend + NN + 8;                  // NBUCK

    gat_init_cursor<<<1, 256, 0, stream>>>(bcursor);
    gat_bin_pass<<<NCHUNK, 256, 0, stream>>>(ei, bcursor, binned);
    gat_fine_pass<<<NBUCK, 256, 0, stream>>>(binned, bcursor, rowstart, rowend, csr16);

    gat_proj_mfma<<<PTILES, 512, 0, stream>>>(x, Wl, Wr, xl, xr);

    gat_aggregate_kernel<<<(NN + 15) / 16, 256, 0, stream>>>(
        xl, xr, att, bias, rowstart, rowend, csr16, out);
}

// Round 13
// 83.855 us; speedup vs baseline: 1.0508x; 1.0508x over previous
//
#include <hip/hip_runtime.h>
#include <hip/hip_fp16.h>
#include <math.h>

// GATv2Conv forward. fp16 xl/xr; padded-bucket CSR (u32 binned, u16 csr);
// merged MFMA proj; aggregate: 32 thr/node, 4-deep load pipeline, SINGLE
// accumulator set (low VGPR -> high occupancy), exp2-folded attention.

#define NN 50000
#define NE 800000
#define NHEADS 8
#define CH 16
#define FDIM 128
#define NEG_SLOPE 0.2f
#define LOG2E 1.44269504088896f

#define BSHIFT 8
#define NBUCK ((NN + 255) >> 8)           // 196 coarse buckets (dst>>8)
#define BCAP 5120                          // mean 4082, sigma 64 -> 16 sigma
#define CHUNK 4096
#define NCHUNK ((NE + CHUNK - 1) / CHUNK)  // 196

typedef _Float16 half8 __attribute__((ext_vector_type(8)));
typedef _Float16 h2v  __attribute__((ext_vector_type(2)));
typedef float f32x4 __attribute__((ext_vector_type(4)));

// ---------------- projection GEMM via MFMA (merged Wl+Wr) ----------------
#define PBM 64
#define PTILES ((NN + PBM - 1) / PBM)   // 782

__global__ __launch_bounds__(512) void gat_proj_mfma(
        const float* __restrict__ x,
        const float* __restrict__ Wl,
        const float* __restrict__ Wr,
        __half* __restrict__ xl,
        __half* __restrict__ xr) {
    __shared__ __half Al[PBM][FDIM];    // 16 KB, 16B-chunk XOR-swizzled
    __shared__ __half Bl[256][FDIM];    // 64 KB, rows 0..127 Wl, 128..255 Wr

    const int t    = threadIdx.x;
    const int lane = t & 63;
    const int wave = t >> 6;            // 0..7
    const int wm   = wave >> 2;         // 0..1
    const int wn   = wave & 3;          // 0..3
    const int lr   = lane & 15;
    const int lh   = lane >> 4;

    const int row0 = blockIdx.x * PBM;

    #pragma unroll
    for (int i = 0; i < 2; ++i) {
        int c   = t + i * 512;
        int row = c >> 4;
        int c16 = c & 15;
        int sc  = c16 ^ (row & 7);
        int arow = row0 + row;
        if (arow >= NN) arow = NN - 1;
        const float4* src = reinterpret_cast<const float4*>(
            x + (size_t)arow * FDIM + c16 * 8);
        float4 v0 = src[0];
        float4 v1 = src[1];
        union { uint4 u; __half2 h[4]; } pk;
        pk.h[0] = __floats2half2_rn(v0.x, v0.y);
        pk.h[1] = __floats2half2_rn(v0.z, v0.w);
        pk.h[2] = __floats2half2_rn(v1.x, v1.y);
        pk.h[3] = __floats2half2_rn(v1.z, v1.w);
        *reinterpret_cast<uint4*>(&Al[row][sc * 8]) = pk.u;
    }
    #pragma unroll
    for (int i = 0; i < 8; ++i) {
        int c   = t + i * 512;
        int row = c >> 4;               // 0..255
        int c16 = c & 15;
        int sc  = c16 ^ (row & 7);
        const float* wr = (row < 128) ? (Wl + (size_t)row * FDIM)
                                      : (Wr + (size_t)(row - 128) * FDIM);
        const float4* src = reinterpret_cast<const float4*>(wr + c16 * 8);
        float4 v0 = src[0];
        float4 v1 = src[1];
        union { uint4 u; __half2 h[4]; } pk;
        pk.h[0] = __floats2half2_rn(v0.x, v0.y);
        pk.h[1] = __floats2half2_rn(v0.z, v0.w);
        pk.h[2] = __floats2half2_rn(v1.x, v1.y);
        pk.h[3] = __floats2half2_rn(v1.z, v1.w);
        *reinterpret_cast<uint4*>(&Bl[row][sc * 8]) = pk.u;
    }
    __syncthreads();

    f32x4 acc[2][4] = {};
    const char* Ab = reinterpret_cast<const char*>(&Al[0][0]);
    const char* Bb = reinterpret_cast<const char*>(&Bl[0][0]);

    #pragma unroll
    for (int kc = 0; kc < 4; ++kc) {
        half8 a[2], b[4];
        #pragma unroll
        for (int mi = 0; mi < 2; ++mi) {
            int row = wm * 32 + mi * 16 + lr;
            int bc  = (kc * 64 + 16 * lh) ^ ((row & 7) << 4);
            a[mi] = *reinterpret_cast<const half8*>(Ab + row * 256 + bc);
        }
        #pragma unroll
        for (int ni = 0; ni < 4; ++ni) {
            int row = wn * 64 + ni * 16 + lr;
            int bc  = (kc * 64 + 16 * lh) ^ ((row & 7) << 4);
            b[ni] = *reinterpret_cast<const half8*>(Bb + row * 256 + bc);
        }
        #pragma unroll
        for (int mi = 0; mi < 2; ++mi)
            #pragma unroll
            for (int ni = 0; ni < 4; ++ni)
                acc[mi][ni] = __builtin_amdgcn_mfma_f32_16x16x32_f16(
                    a[mi], b[ni], acc[mi][ni], 0, 0, 0);
    }

    #pragma unroll
    for (int mi = 0; mi < 2; ++mi) {
        #pragma unroll
        for (int ni = 0; ni < 4; ++ni) {
            int gc = wn * 64 + ni * 16 + lr;
            __half* outp = (gc < 128) ? xl : xr;
            int col = gc & 127;
            #pragma unroll
            for (int r = 0; r < 4; ++r) {
                int grow = row0 + wm * 32 + mi * 16 + 4 * lh + r;
                if (grow < NN)
                    outp[(size_t)grow * FDIM + col] = __float2half(acc[mi][ni][r]);
            }
        }
    }
}

// ---------------- CSR build: padded buckets, packed u32/u16 --------------
__global__ void gat_init_cursor(int* __restrict__ bcursor) {
    int t = threadIdx.x;
    if (t < NBUCK) bcursor[t] = t * BCAP;
}

__global__ __launch_bounds__(256) void gat_bin_pass(
        const int* __restrict__ ei,
        int* __restrict__ bcursor,
        unsigned* __restrict__ binned) {
    __shared__ int hist[NBUCK];
    __shared__ int base_l[NBUCK];
    int t = threadIdx.x;
    for (int i = t; i < NBUCK; i += 256) hist[i] = 0;
    __syncthreads();

    int cbase = blockIdx.x * CHUNK;
    int s[CHUNK / 256], d[CHUNK / 256], r[CHUNK / 256];
    #pragma unroll
    for (int i = 0; i < CHUNK / 256; ++i) {
        int m = cbase + i * 256 + t;
        if (m < NE) {
            s[i] = ei[m];
            d[i] = ei[NE + m];
            r[i] = atomicAdd(&hist[d[i] >> BSHIFT], 1);
        } else {
            d[i] = -1;
        }
    }
    __syncthreads();
    for (int i = t; i < NBUCK; i += 256)
        base_l[i] = hist[i] ? atomicAdd(&bcursor[i], hist[i]) : 0;
    __syncthreads();
    #pragma unroll
    for (int i = 0; i < CHUNK / 256; ++i) {
        if (d[i] >= 0) {
            int pos = base_l[d[i] >> BSHIFT] + r[i];
            binned[pos] = ((unsigned)s[i] << 8) | (unsigned)(d[i] & 255);
        }
    }
}

__global__ __launch_bounds__(256) void gat_fine_pass(
        const unsigned* __restrict__ binned,
        const int* __restrict__ bcursor,
        int* __restrict__ rowstart,
        int* __restrict__ rowend,
        unsigned short* __restrict__ csr16) {
    __shared__ unsigned ebuf[BCAP];     // 20 KB
    __shared__ int cnt_c[256];
    __shared__ int sbuf[256];
    __shared__ int cur_c[256];
    int t = threadIdx.x;
    int b = blockIdx.x;
    int base = b * BCAP;
    int cnt  = bcursor[b] - base;

    for (int j = t; j < cnt; j += 256) ebuf[j] = binned[base + j];
    cnt_c[t] = 0;
    __syncthreads();
    for (int j = t; j < cnt; j += 256)
        atomicAdd(&cnt_c[ebuf[j] & 255u], 1);
    __syncthreads();

    int v = cnt_c[t];
    sbuf[t] = v;
    __syncthreads();
    for (int off = 1; off < 256; off <<= 1) {
        int add = (t >= off) ? sbuf[t - off] : 0;
        __syncthreads();
        sbuf[t] += add;
        __syncthreads();
    }
    int excl = sbuf[t] - v;
    cur_c[t] = excl;
    int node = (b << BSHIFT) + t;
    if (node < NN) {
        rowstart[node] = base + excl;
        rowend[node]   = base + excl + v;
    }
    __syncthreads();

    for (int j = t; j < cnt; j += 256) {
        unsigned e = ebuf[j];
        int pos = atomicAdd(&cur_c[e & 255u], 1);
        csr16[base + pos] = (unsigned short)(e >> 8);
    }
}

// ---------------- fused aggregate: 32 thr/node, single-acc ---------------
// leaky(s) = 0.6*s + 0.4*|s| (exact for slope 0.2); att pre-scaled by log2e
// so ea = exp2(p) = v_exp_f32 directly.
__device__ __forceinline__ void gat_edge_step_h(
        const h2v xi01, const h2v xi23,
        const h2v at01, const h2v at23,
        uint2 raw, float4& acc, float& den) {
    union uh { unsigned u; h2v v; };
    uh j01, j23;
    j01.u = raw.x; j23.u = raw.y;
    h2v s01 = xi01 + j01.v;
    h2v s23 = xi23 + j23.v;
    uh b01, b23, a01, a23;
    b01.v = s01; b23.v = s23;
    a01.u = b01.u & 0x7FFF7FFFu;
    a23.u = b23.u & 0x7FFF7FFFu;
    const h2v c1 = {(_Float16)0.6f, (_Float16)0.6f};
    const h2v c2 = {(_Float16)0.4f, (_Float16)0.4f};
    h2v e01 = s01 * c1 + a01.v * c2;
    h2v e23 = s23 * c1 + a23.v * c2;
#if __has_builtin(__builtin_amdgcn_fdot2)
    float p = __builtin_amdgcn_fdot2(e01, at01, 0.0f, false);
    p = __builtin_amdgcn_fdot2(e23, at23, p, false);
#else
    float p = (float)e01[0] * (float)at01[0] + (float)e01[1] * (float)at01[1]
            + (float)e23[0] * (float)at23[0] + (float)e23[1] * (float)at23[1];
#endif
    p += __shfl_xor(p, 1);
    p += __shfl_xor(p, 2);
    float ea = exp2f(p);
    acc.x = fmaf((float)j01.v[0], ea, acc.x);
    acc.y = fmaf((float)j01.v[1], ea, acc.y);
    acc.z = fmaf((float)j23.v[0], ea, acc.z);
    acc.w = fmaf((float)j23.v[1], ea, acc.w);
    den += ea;
}

__global__ __launch_bounds__(256) void gat_aggregate_kernel(
        const __half* __restrict__ xl,
        const __half* __restrict__ xr,
        const float* __restrict__ att,
        const float* __restrict__ bias,
        const int* __restrict__ rowstart,
        const int* __restrict__ rowend,
        const unsigned short* __restrict__ csr16,
        float* __restrict__ out) {
    int node = blockIdx.x * 8 + (threadIdx.x >> 5);
    int u = threadIdx.x & 31;
    if (node >= NN) return;

    union uh { unsigned u; h2v v; };
    uint2 xiraw = *reinterpret_cast<const uint2*>(xr + (size_t)node * FDIM + u * 4);
    uh xi0, xi1;
    xi0.u = xiraw.x; xi1.u = xiraw.y;
    const float4 atf = *reinterpret_cast<const float4*>(att + u * 4);
    h2v a01 = {(_Float16)(atf.x * LOG2E), (_Float16)(atf.y * LOG2E)};
    h2v a23 = {(_Float16)(atf.z * LOG2E), (_Float16)(atf.w * LOG2E)};
    const float4 bi = *reinterpret_cast<const float4*>(bias + u * 4);
    int e0 = rowstart[node];
    int e1 = rowend[node];

    float4 acc = {0, 0, 0, 0};
    float den = 0.0f;

    int e = e0;
    for (; e + 4 <= e1; e += 4) {
        int s0 = csr16[e + 0];
        int s1 = csr16[e + 1];
        int s2 = csr16[e + 2];
        int s3 = csr16[e + 3];
        uint2 r0 = *reinterpret_cast<const uint2*>(xl + (size_t)s0 * FDIM + u * 4);
        uint2 r1 = *reinterpret_cast<const uint2*>(xl + (size_t)s1 * FDIM + u * 4);
        uint2 r2 = *reinterpret_cast<const uint2*>(xl + (size_t)s2 * FDIM + u * 4);
        uint2 r3 = *reinterpret_cast<const uint2*>(xl + (size_t)s3 * FDIM + u * 4);
        gat_edge_step_h(xi0.v, xi1.v, a01, a23, r0, acc, den);
        gat_edge_step_h(xi0.v, xi1.v, a01, a23, r1, acc, den);
        gat_edge_step_h(xi0.v, xi1.v, a01, a23, r2, acc, den);
        gat_edge_step_h(xi0.v, xi1.v, a01, a23, r3, acc, den);
    }
    for (; e < e1; ++e) {
        int s0 = csr16[e];
        uint2 r0 = *reinterpret_cast<const uint2*>(xl + (size_t)s0 * FDIM + u * 4);
        gat_edge_step_h(xi0.v, xi1.v, a01, a23, r0, acc, den);
    }

    float inv = 1.0f / (den + 1e-16f);
    float4 o;
    o.x = acc.x * inv + bi.x;
    o.y = acc.y * inv + bi.y;
    o.z = acc.z * inv + bi.z;
    o.w = acc.w * inv + bi.w;
    *reinterpret_cast<float4*>(out + (size_t)node * FDIM + u * 4) = o;
}

extern "C" void kernel_launch(void* const* d_in, const int* in_sizes, int n_in,
                              void* d_out, int out_size, void* d_ws, size_t ws_size,
                              hipStream_t stream) {
    const float* x    = (const float*)d_in[0];
    const int*   ei   = (const int*)d_in[1];
    const float* Wl   = (const float*)d_in[2];
    const float* Wr   = (const float*)d_in[3];
    const float* att  = (const float*)d_in[4];
    const float* bias = (const float*)d_in[5];
    float* out = (float*)d_out;

    // ws layout (d_ws 256-aligned)
    __half* xl = (__half*)d_ws;                        // 12.8 MB
    __half* xr = xl + (size_t)NN * FDIM;               // 12.8 MB
    unsigned* binned = (unsigned*)(xr + (size_t)NN * FDIM); // NBUCK*BCAP u32 (4 MB)
    unsigned short* csr16 = (unsigned short*)(binned + (size_t)NBUCK * BCAP); // 2 MB
    int* rowstart  = (int*)(csr16 + (size_t)NBUCK * BCAP); // NN
    int* rowend    = rowstart + NN + 8;                // NN
    int* bcursor   = rowend + NN + 8;                  // NBUCK

    gat_init_cursor<<<1, 256, 0, stream>>>(bcursor);
    gat_bin_pass<<<NCHUNK, 256, 0, stream>>>(ei, bcursor, binned);
    gat_fine_pass<<<NBUCK, 256, 0, stream>>>(binned, bcursor, rowstart, rowend, csr16);

    gat_proj_mfma<<<PTILES, 512, 0, stream>>>(x, Wl, Wr, xl, xr);

    gat_aggregate_kernel<<<(NN + 7) / 8, 256, 0, stream>>>(
        xl, xr, att, bias, rowstart, rowend, csr16, out);
}

// Round 14
// 75.202 us; speedup vs baseline: 1.1717x; 1.1151x over previous
//
#include <hip/hip_runtime.h>
#include <hip/hip_fp16.h>
#include <math.h>

// GATv2Conv forward. fp16 xl/xr; padded-bucket CSR (u32 binned, u16 csr);
// FUSED {MFMA proj ∥ bin_pass} kernel (block-partitioned, shared LDS buffer);
// aggregate: 32 thr/node, single-acc, exp2-folded attention.

#define NN 50000
#define NE 800000
#define NHEADS 8
#define CH 16
#define FDIM 128
#define NEG_SLOPE 0.2f
#define LOG2E 1.44269504088896f

#define BSHIFT 8
#define NBUCK ((NN + 255) >> 8)           // 196 coarse buckets (dst>>8)
#define BCAP 5120                          // mean 4082, sigma 64 -> 16 sigma
#define CHUNK 4096
#define NCHUNK ((NE + CHUNK - 1) / CHUNK)  // 196

typedef _Float16 half8 __attribute__((ext_vector_type(8)));
typedef _Float16 h2v  __attribute__((ext_vector_type(2)));
typedef float f32x4 __attribute__((ext_vector_type(4)));

#define PBM 64
#define PTILES ((NN + PBM - 1) / PBM)   // 782

// ---------------- fused: bin_pass (blocks 0..NCHUNK-1) ∥ proj (rest) -----
__global__ __launch_bounds__(512) void gat_fused_proj_bin(
        const float* __restrict__ x,
        const float* __restrict__ Wl,
        const float* __restrict__ Wr,
        const int* __restrict__ ei,
        int* __restrict__ bcursor,
        unsigned* __restrict__ binned,
        __half* __restrict__ xl,
        __half* __restrict__ xr) {
    __shared__ char smem[81920];       // 80 KB shared by both paths
    const int t = threadIdx.x;

    if ((int)blockIdx.x < NCHUNK) {
        // ================= bin path (512 threads, 8 edges/thread) ========
        int* hist   = reinterpret_cast<int*>(smem);            // NBUCK
        int* base_l = hist + 256;                              // NBUCK
        for (int i = t; i < NBUCK; i += 512) hist[i] = 0;
        __syncthreads();

        int cbase = blockIdx.x * CHUNK;
        int s[CHUNK / 512], d[CHUNK / 512], r[CHUNK / 512];
        #pragma unroll
        for (int i = 0; i < CHUNK / 512; ++i) {
            int m = cbase + i * 512 + t;
            if (m < NE) {
                s[i] = ei[m];
                d[i] = ei[NE + m];
                r[i] = atomicAdd(&hist[d[i] >> BSHIFT], 1);
            } else {
                d[i] = -1;
            }
        }
        __syncthreads();
        for (int i = t; i < NBUCK; i += 512)
            base_l[i] = hist[i] ? atomicAdd(&bcursor[i], hist[i]) : 0;
        __syncthreads();
        #pragma unroll
        for (int i = 0; i < CHUNK / 512; ++i) {
            if (d[i] >= 0) {
                int pos = base_l[d[i] >> BSHIFT] + r[i];
                binned[pos] = ((unsigned)s[i] << 8) | (unsigned)(d[i] & 255);
            }
        }
        return;
    }

    // ================= proj path (MFMA, merged Wl+Wr) ====================
    __half (*Al)[FDIM] = reinterpret_cast<__half (*)[FDIM]>(smem);           // 16 KB
    __half (*Bl)[FDIM] = reinterpret_cast<__half (*)[FDIM]>(smem + 16384);   // 64 KB

    const int lane = t & 63;
    const int wave = t >> 6;            // 0..7
    const int wm   = wave >> 2;         // 0..1
    const int wn   = wave & 3;          // 0..3
    const int lr   = lane & 15;
    const int lh   = lane >> 4;
    const int row0 = ((int)blockIdx.x - NCHUNK) * PBM;

    #pragma unroll
    for (int i = 0; i < 2; ++i) {
        int c   = t + i * 512;
        int row = c >> 4;
        int c16 = c & 15;
        int sc  = c16 ^ (row & 7);
        int arow = row0 + row;
        if (arow >= NN) arow = NN - 1;
        const float4* src = reinterpret_cast<const float4*>(
            x + (size_t)arow * FDIM + c16 * 8);
        float4 v0 = src[0];
        float4 v1 = src[1];
        union { uint4 u; __half2 h[4]; } pk;
        pk.h[0] = __floats2half2_rn(v0.x, v0.y);
        pk.h[1] = __floats2half2_rn(v0.z, v0.w);
        pk.h[2] = __floats2half2_rn(v1.x, v1.y);
        pk.h[3] = __floats2half2_rn(v1.z, v1.w);
        *reinterpret_cast<uint4*>(&Al[row][sc * 8]) = pk.u;
    }
    #pragma unroll
    for (int i = 0; i < 8; ++i) {
        int c   = t + i * 512;
        int row = c >> 4;               // 0..255
        int c16 = c & 15;
        int sc  = c16 ^ (row & 7);
        const float* wr = (row < 128) ? (Wl + (size_t)row * FDIM)
                                      : (Wr + (size_t)(row - 128) * FDIM);
        const float4* src = reinterpret_cast<const float4*>(wr + c16 * 8);
        float4 v0 = src[0];
        float4 v1 = src[1];
        union { uint4 u; __half2 h[4]; } pk;
        pk.h[0] = __floats2half2_rn(v0.x, v0.y);
        pk.h[1] = __floats2half2_rn(v0.z, v0.w);
        pk.h[2] = __floats2half2_rn(v1.x, v1.y);
        pk.h[3] = __floats2half2_rn(v1.z, v1.w);
        *reinterpret_cast<uint4*>(&Bl[row][sc * 8]) = pk.u;
    }
    __syncthreads();

    f32x4 acc[2][4] = {};
    const char* Ab = reinterpret_cast<const char*>(&Al[0][0]);
    const char* Bb = reinterpret_cast<const char*>(&Bl[0][0]);

    #pragma unroll
    for (int kc = 0; kc < 4; ++kc) {
        half8 a[2], b[4];
        #pragma unroll
        for (int mi = 0; mi < 2; ++mi) {
            int row = wm * 32 + mi * 16 + lr;
            int bc  = (kc * 64 + 16 * lh) ^ ((row & 7) << 4);
            a[mi] = *reinterpret_cast<const half8*>(Ab + row * 256 + bc);
        }
        #pragma unroll
        for (int ni = 0; ni < 4; ++ni) {
            int row = wn * 64 + ni * 16 + lr;
            int bc  = (kc * 64 + 16 * lh) ^ ((row & 7) << 4);
            b[ni] = *reinterpret_cast<const half8*>(Bb + row * 256 + bc);
        }
        #pragma unroll
        for (int mi = 0; mi < 2; ++mi)
            #pragma unroll
            for (int ni = 0; ni < 4; ++ni)
                acc[mi][ni] = __builtin_amdgcn_mfma_f32_16x16x32_f16(
                    a[mi], b[ni], acc[mi][ni], 0, 0, 0);
    }

    #pragma unroll
    for (int mi = 0; mi < 2; ++mi) {
        #pragma unroll
        for (int ni = 0; ni < 4; ++ni) {
            int gc = wn * 64 + ni * 16 + lr;
            __half* outp = (gc < 128) ? xl : xr;
            int col = gc & 127;
            #pragma unroll
            for (int r = 0; r < 4; ++r) {
                int grow = row0 + wm * 32 + mi * 16 + 4 * lh + r;
                if (grow < NN)
                    outp[(size_t)grow * FDIM + col] = __float2half(acc[mi][ni][r]);
            }
        }
    }
}

// ---------------- init + fine pass ---------------------------------------
__global__ void gat_init_cursor(int* __restrict__ bcursor) {
    int t = threadIdx.x;
    if (t < NBUCK) bcursor[t] = t * BCAP;
}

__global__ __launch_bounds__(256) void gat_fine_pass(
        const unsigned* __restrict__ binned,
        const int* __restrict__ bcursor,
        int* __restrict__ rowstart,
        int* __restrict__ rowend,
        unsigned short* __restrict__ csr16) {
    __shared__ unsigned ebuf[BCAP];     // 20 KB
    __shared__ int cnt_c[256];
    __shared__ int sbuf[256];
    __shared__ int cur_c[256];
    int t = threadIdx.x;
    int b = blockIdx.x;
    int base = b * BCAP;
    int cnt  = bcursor[b] - base;

    for (int j = t; j < cnt; j += 256) ebuf[j] = binned[base + j];
    cnt_c[t] = 0;
    __syncthreads();
    for (int j = t; j < cnt; j += 256)
        atomicAdd(&cnt_c[ebuf[j] & 255u], 1);
    __syncthreads();

    int v = cnt_c[t];
    sbuf[t] = v;
    __syncthreads();
    for (int off = 1; off < 256; off <<= 1) {
        int add = (t >= off) ? sbuf[t - off] : 0;
        __syncthreads();
        sbuf[t] += add;
        __syncthreads();
    }
    int excl = sbuf[t] - v;
    cur_c[t] = excl;
    int node = (b << BSHIFT) + t;
    if (node < NN) {
        rowstart[node] = base + excl;
        rowend[node]   = base + excl + v;
    }
    __syncthreads();

    for (int j = t; j < cnt; j += 256) {
        unsigned e = ebuf[j];
        int pos = atomicAdd(&cur_c[e & 255u], 1);
        csr16[base + pos] = (unsigned short)(e >> 8);
    }
}

// ---------------- fused aggregate: 32 thr/node, single-acc ---------------
__device__ __forceinline__ void gat_edge_step_h(
        const h2v xi01, const h2v xi23,
        const h2v at01, const h2v at23,
        uint2 raw, float4& acc, float& den) {
    union uh { unsigned u; h2v v; };
    uh j01, j23;
    j01.u = raw.x; j23.u = raw.y;
    h2v s01 = xi01 + j01.v;
    h2v s23 = xi23 + j23.v;
    uh b01, b23, a01, a23;
    b01.v = s01; b23.v = s23;
    a01.u = b01.u & 0x7FFF7FFFu;
    a23.u = b23.u & 0x7FFF7FFFu;
    const h2v c1 = {(_Float16)0.6f, (_Float16)0.6f};
    const h2v c2 = {(_Float16)0.4f, (_Float16)0.4f};
    h2v e01 = s01 * c1 + a01.v * c2;
    h2v e23 = s23 * c1 + a23.v * c2;
#if __has_builtin(__builtin_amdgcn_fdot2)
    float p = __builtin_amdgcn_fdot2(e01, at01, 0.0f, false);
    p = __builtin_amdgcn_fdot2(e23, at23, p, false);
#else
    float p = (float)e01[0] * (float)at01[0] + (float)e01[1] * (float)at01[1]
            + (float)e23[0] * (float)at23[0] + (float)e23[1] * (float)at23[1];
#endif
    p += __shfl_xor(p, 1);
    p += __shfl_xor(p, 2);
    float ea = exp2f(p);
    acc.x = fmaf((float)j01.v[0], ea, acc.x);
    acc.y = fmaf((float)j01.v[1], ea, acc.y);
    acc.z = fmaf((float)j23.v[0], ea, acc.z);
    acc.w = fmaf((float)j23.v[1], ea, acc.w);
    den += ea;
}

__global__ __launch_bounds__(256) void gat_aggregate_kernel(
        const __half* __restrict__ xl,
        const __half* __restrict__ xr,
        const float* __restrict__ att,
        const float* __restrict__ bias,
        const int* __restrict__ rowstart,
        const int* __restrict__ rowend,
        const unsigned short* __restrict__ csr16,
        float* __restrict__ out) {
    int node = blockIdx.x * 8 + (threadIdx.x >> 5);
    int u = threadIdx.x & 31;
    if (node >= NN) return;

    union uh { unsigned u; h2v v; };
    uint2 xiraw = *reinterpret_cast<const uint2*>(xr + (size_t)node * FDIM + u * 4);
    uh xi0, xi1;
    xi0.u = xiraw.x; xi1.u = xiraw.y;
    const float4 atf = *reinterpret_cast<const float4*>(att + u * 4);
    h2v a01 = {(_Float16)(atf.x * LOG2E), (_Float16)(atf.y * LOG2E)};
    h2v a23 = {(_Float16)(atf.z * LOG2E), (_Float16)(atf.w * LOG2E)};
    const float4 bi = *reinterpret_cast<const float4*>(bias + u * 4);
    int e0 = rowstart[node];
    int e1 = rowend[node];

    float4 acc = {0, 0, 0, 0};
    float den = 0.0f;

    int e = e0;
    for (; e + 4 <= e1; e += 4) {
        int s0 = csr16[e + 0];
        int s1 = csr16[e + 1];
        int s2 = csr16[e + 2];
        int s3 = csr16[e + 3];
        uint2 r0 = *reinterpret_cast<const uint2*>(xl + (size_t)s0 * FDIM + u * 4);
        uint2 r1 = *reinterpret_cast<const uint2*>(xl + (size_t)s1 * FDIM + u * 4);
        uint2 r2 = *reinterpret_cast<const uint2*>(xl + (size_t)s2 * FDIM + u * 4);
        uint2 r3 = *reinterpret_cast<const uint2*>(xl + (size_t)s3 * FDIM + u * 4);
        gat_edge_step_h(xi0.v, xi1.v, a01, a23, r0, acc, den);
        gat_edge_step_h(xi0.v, xi1.v, a01, a23, r1, acc, den);
        gat_edge_step_h(xi0.v, xi1.v, a01, a23, r2, acc, den);
        gat_edge_step_h(xi0.v, xi1.v, a01, a23, r3, acc, den);
    }
    for (; e < e1; ++e) {
        int s0 = csr16[e];
        uint2 r0 = *reinterpret_cast<const uint2*>(xl + (size_t)s0 * FDIM + u * 4);
        gat_edge_step_h(xi0.v, xi1.v, a01, a23, r0, acc, den);
    }

    float inv = 1.0f / (den + 1e-16f);
    float4 o;
    o.x = acc.x * inv + bi.x;
    o.y = acc.y * inv + bi.y;
    o.z = acc.z * inv + bi.z;
    o.w = acc.w * inv + bi.w;
    *reinterpret_cast<float4*>(out + (size_t)node * FDIM + u * 4) = o;
}

extern "C" void kernel_launch(void* const* d_in, const int* in_sizes, int n_in,
                              void* d_out, int out_size, void* d_ws, size_t ws_size,
                              hipStream_t stream) {
    const float* x    = (const float*)d_in[0];
    const int*   ei   = (const int*)d_in[1];
    const float* Wl   = (const float*)d_in[2];
    const float* Wr   = (const float*)d_in[3];
    const float* att  = (const float*)d_in[4];
    const float* bias = (const float*)d_in[5];
    float* out = (float*)d_out;

    // ws layout (d_ws 256-aligned)
    __half* xl = (__half*)d_ws;                        // 12.8 MB
    __half* xr = xl + (size_t)NN * FDIM;               // 12.8 MB
    unsigned* binned = (unsigned*)(xr + (size_t)NN * FDIM); // NBUCK*BCAP u32 (4 MB)
    unsigned short* csr16 = (unsigned short*)(binned + (size_t)NBUCK * BCAP); // 2 MB
    int* rowstart  = (int*)(csr16 + (size_t)NBUCK * BCAP); // NN
    int* rowend    = rowstart + NN + 8;                // NN
    int* bcursor   = rowend + NN + 8;                  // NBUCK

    gat_init_cursor<<<1, 256, 0, stream>>>(bcursor);
    gat_fused_proj_bin<<<NCHUNK + PTILES, 512, 0, stream>>>(
        x, Wl, Wr, ei, bcursor, binned, xl, xr);
    gat_fine_pass<<<NBUCK, 256, 0, stream>>>(binned, bcursor, rowstart, rowend, csr16);
    gat_aggregate_kernel<<<(NN + 7) / 8, 256, 0, stream>>>(
        xl, xr, att, bias, rowstart, rowend, csr16, out);
}

// Round 15
// 74.979 us; speedup vs baseline: 1.1752x; 1.0030x over previous
//
#include <hip/hip_runtime.h>
#include <hip/hip_fp16.h>
#include <math.h>

// GATv2Conv forward. fp16 xl/xr; padded-bucket CSR (u32 binned, u16 csr);
// FUSED {MFMA proj ∥ bin_pass}; memset-based cursor init (no init kernel);
// fine_pass 512 threads; aggregate: 32 thr/node, single-acc, exp2 attention.

#define NN 50000
#define NE 800000
#define NHEADS 8
#define CH 16
#define FDIM 128
#define NEG_SLOPE 0.2f
#define LOG2E 1.44269504088896f

#define BSHIFT 8
#define NBUCK ((NN + 255) >> 8)           // 196 coarse buckets (dst>>8)
#define BCAP 5120                          // mean 4082, sigma 64 -> 16 sigma
#define CHUNK 4096
#define NCHUNK ((NE + CHUNK - 1) / CHUNK)  // 196

typedef _Float16 half8 __attribute__((ext_vector_type(8)));
typedef _Float16 h2v  __attribute__((ext_vector_type(2)));
typedef float f32x4 __attribute__((ext_vector_type(4)));

#define PBM 64
#define PTILES ((NN + PBM - 1) / PBM)   // 782

// ---------------- fused: bin_pass (blocks 0..NCHUNK-1) ∥ proj (rest) -----
__global__ __launch_bounds__(512) void gat_fused_proj_bin(
        const float* __restrict__ x,
        const float* __restrict__ Wl,
        const float* __restrict__ Wr,
        const int* __restrict__ ei,
        int* __restrict__ bcursor,        // zeroed counts
        unsigned* __restrict__ binned,
        __half* __restrict__ xl,
        __half* __restrict__ xr) {
    __shared__ char smem[81920];       // 80 KB shared by both paths
    const int t = threadIdx.x;

    if ((int)blockIdx.x < NCHUNK) {
        // ================= bin path (512 threads, 8 edges/thread) ========
        int* hist   = reinterpret_cast<int*>(smem);            // 256
        int* base_l = hist + 256;                              // 256
        for (int i = t; i < NBUCK; i += 512) hist[i] = 0;
        __syncthreads();

        int cbase = blockIdx.x * CHUNK;
        int s[CHUNK / 512], d[CHUNK / 512], r[CHUNK / 512];
        #pragma unroll
        for (int i = 0; i < CHUNK / 512; ++i) {
            int m = cbase + i * 512 + t;
            if (m < NE) {
                s[i] = ei[m];
                d[i] = ei[NE + m];
                r[i] = atomicAdd(&hist[d[i] >> BSHIFT], 1);
            } else {
                d[i] = -1;
            }
        }
        __syncthreads();
        for (int i = t; i < NBUCK; i += 512)
            base_l[i] = hist[i] ? (i * BCAP + atomicAdd(&bcursor[i], hist[i])) : 0;
        __syncthreads();
        #pragma unroll
        for (int i = 0; i < CHUNK / 512; ++i) {
            if (d[i] >= 0) {
                int pos = base_l[d[i] >> BSHIFT] + r[i];
                binned[pos] = ((unsigned)s[i] << 8) | (unsigned)(d[i] & 255);
            }
        }
        return;
    }

    // ================= proj path (MFMA, merged Wl+Wr) ====================
    __half (*Al)[FDIM] = reinterpret_cast<__half (*)[FDIM]>(smem);           // 16 KB
    __half (*Bl)[FDIM] = reinterpret_cast<__half (*)[FDIM]>(smem + 16384);   // 64 KB

    const int lane = t & 63;
    const int wave = t >> 6;            // 0..7
    const int wm   = wave >> 2;         // 0..1
    const int wn   = wave & 3;          // 0..3
    const int lr   = lane & 15;
    const int lh   = lane >> 4;
    const int row0 = ((int)blockIdx.x - NCHUNK) * PBM;

    #pragma unroll
    for (int i = 0; i < 2; ++i) {
        int c   = t + i * 512;
        int row = c >> 4;
        int c16 = c & 15;
        int sc  = c16 ^ (row & 7);
        int arow = row0 + row;
        if (arow >= NN) arow = NN - 1;
        const float4* src = reinterpret_cast<const float4*>(
            x + (size_t)arow * FDIM + c16 * 8);
        float4 v0 = src[0];
        float4 v1 = src[1];
        union { uint4 u; __half2 h[4]; } pk;
        pk.h[0] = __floats2half2_rn(v0.x, v0.y);
        pk.h[1] = __floats2half2_rn(v0.z, v0.w);
        pk.h[2] = __floats2half2_rn(v1.x, v1.y);
        pk.h[3] = __floats2half2_rn(v1.z, v1.w);
        *reinterpret_cast<uint4*>(&Al[row][sc * 8]) = pk.u;
    }
    #pragma unroll
    for (int i = 0; i < 8; ++i) {
        int c   = t + i * 512;
        int row = c >> 4;               // 0..255
        int c16 = c & 15;
        int sc  = c16 ^ (row & 7);
        const float* wr = (row < 128) ? (Wl + (size_t)row * FDIM)
                                      : (Wr + (size_t)(row - 128) * FDIM);
        const float4* src = reinterpret_cast<const float4*>(wr + c16 * 8);
        float4 v0 = src[0];
        float4 v1 = src[1];
        union { uint4 u; __half2 h[4]; } pk;
        pk.h[0] = __floats2half2_rn(v0.x, v0.y);
        pk.h[1] = __floats2half2_rn(v0.z, v0.w);
        pk.h[2] = __floats2half2_rn(v1.x, v1.y);
        pk.h[3] = __floats2half2_rn(v1.z, v1.w);
        *reinterpret_cast<uint4*>(&Bl[row][sc * 8]) = pk.u;
    }
    __syncthreads();

    f32x4 acc[2][4] = {};
    const char* Ab = reinterpret_cast<const char*>(&Al[0][0]);
    const char* Bb = reinterpret_cast<const char*>(&Bl[0][0]);

    #pragma unroll
    for (int kc = 0; kc < 4; ++kc) {
        half8 a[2], b[4];
        #pragma unroll
        for (int mi = 0; mi < 2; ++mi) {
            int row = wm * 32 + mi * 16 + lr;
            int bc  = (kc * 64 + 16 * lh) ^ ((row & 7) << 4);
            a[mi] = *reinterpret_cast<const half8*>(Ab + row * 256 + bc);
        }
        #pragma unroll
        for (int ni = 0; ni < 4; ++ni) {
            int row = wn * 64 + ni * 16 + lr;
            int bc  = (kc * 64 + 16 * lh) ^ ((row & 7) << 4);
            b[ni] = *reinterpret_cast<const half8*>(Bb + row * 256 + bc);
        }
        #pragma unroll
        for (int mi = 0; mi < 2; ++mi)
            #pragma unroll
            for (int ni = 0; ni < 4; ++ni)
                acc[mi][ni] = __builtin_amdgcn_mfma_f32_16x16x32_f16(
                    a[mi], b[ni], acc[mi][ni], 0, 0, 0);
    }

    #pragma unroll
    for (int mi = 0; mi < 2; ++mi) {
        #pragma unroll
        for (int ni = 0; ni < 4; ++ni) {
            int gc = wn * 64 + ni * 16 + lr;
            __half* outp = (gc < 128) ? xl : xr;
            int col = gc & 127;
            #pragma unroll
            for (int r = 0; r < 4; ++r) {
                int grow = row0 + wm * 32 + mi * 16 + 4 * lh + r;
                if (grow < NN)
                    outp[(size_t)grow * FDIM + col] = __float2half(acc[mi][ni][r]);
            }
        }
    }
}

// ---------------- fine pass (512 threads/bucket) --------------------------
__global__ __launch_bounds__(512) void gat_fine_pass(
        const unsigned* __restrict__ binned,
        const int* __restrict__ bcursor,   // counts
        int* __restrict__ rowstart,
        int* __restrict__ rowend,
        unsigned short* __restrict__ csr16) {
    __shared__ unsigned ebuf[BCAP];     // 20 KB
    __shared__ int cnt_c[256];
    __shared__ int sbuf[512];
    __shared__ int cur_c[256];
    int t = threadIdx.x;
    int b = blockIdx.x;
    int base = b * BCAP;
    int cnt  = bcursor[b];

    for (int j = t; j < cnt; j += 512) ebuf[j] = binned[base + j];
    if (t < 256) cnt_c[t] = 0;
    __syncthreads();
    for (int j = t; j < cnt; j += 512)
        atomicAdd(&cnt_c[ebuf[j] & 255u], 1);
    __syncthreads();

    int v = (t < 256) ? cnt_c[t] : 0;
    sbuf[t] = v;
    __syncthreads();
    for (int off = 1; off < 512; off <<= 1) {
        int add = (t >= off) ? sbuf[t - off] : 0;
        __syncthreads();
        sbuf[t] += add;
        __syncthreads();
    }
    if (t < 256) {
        int excl = sbuf[t] - v;
        cur_c[t] = excl;
        int node = (b << BSHIFT) + t;
        if (node < NN) {
            rowstart[node] = base + excl;
            rowend[node]   = base + excl + v;
        }
    }
    __syncthreads();

    for (int j = t; j < cnt; j += 512) {
        unsigned e = ebuf[j];
        int pos = atomicAdd(&cur_c[e & 255u], 1);
        csr16[base + pos] = (unsigned short)(e >> 8);
    }
}

// ---------------- fused aggregate: 32 thr/node, single-acc ---------------
// leaky(s) = 0.6*s + 0.4*|s| (exact for slope 0.2); att pre-scaled by log2e.
__device__ __forceinline__ void gat_edge_step_h(
        const h2v xi01, const h2v xi23,
        const h2v at01, const h2v at23,
        uint2 raw, float4& acc, float& den) {
    union uh { unsigned u; h2v v; };
    uh j01, j23;
    j01.u = raw.x; j23.u = raw.y;
    h2v s01 = xi01 + j01.v;
    h2v s23 = xi23 + j23.v;
    uh b01, b23, a01, a23;
    b01.v = s01; b23.v = s23;
    a01.u = b01.u & 0x7FFF7FFFu;
    a23.u = b23.u & 0x7FFF7FFFu;
    const h2v c1 = {(_Float16)0.6f, (_Float16)0.6f};
    const h2v c2 = {(_Float16)0.4f, (_Float16)0.4f};
    h2v e01 = s01 * c1 + a01.v * c2;
    h2v e23 = s23 * c1 + a23.v * c2;
#if __has_builtin(__builtin_amdgcn_fdot2)
    float p = __builtin_amdgcn_fdot2(e01, at01, 0.0f, false);
    p = __builtin_amdgcn_fdot2(e23, at23, p, false);
#else
    float p = (float)e01[0] * (float)at01[0] + (float)e01[1] * (float)at01[1]
            + (float)e23[0] * (float)at23[0] + (float)e23[1] * (float)at23[1];
#endif
    p += __shfl_xor(p, 1);
    p += __shfl_xor(p, 2);
    float ea = exp2f(p);
    acc.x = fmaf((float)j01.v[0], ea, acc.x);
    acc.y = fmaf((float)j01.v[1], ea, acc.y);
    acc.z = fmaf((float)j23.v[0], ea, acc.z);
    acc.w = fmaf((float)j23.v[1], ea, acc.w);
    den += ea;
}

__global__ __launch_bounds__(256) void gat_aggregate_kernel(
        const __half* __restrict__ xl,
        const __half* __restrict__ xr,
        const float* __restrict__ att,
        const float* __restrict__ bias,
        const int* __restrict__ rowstart,
        const int* __restrict__ rowend,
        const unsigned short* __restrict__ csr16,
        float* __restrict__ out) {
    int node = blockIdx.x * 8 + (threadIdx.x >> 5);
    int u = threadIdx.x & 31;
    if (node >= NN) return;

    union uh { unsigned u; h2v v; };
    uint2 xiraw = *reinterpret_cast<const uint2*>(xr + (size_t)node * FDIM + u * 4);
    uh xi0, xi1;
    xi0.u = xiraw.x; xi1.u = xiraw.y;
    const float4 atf = *reinterpret_cast<const float4*>(att + u * 4);
    h2v a01 = {(_Float16)(atf.x * LOG2E), (_Float16)(atf.y * LOG2E)};
    h2v a23 = {(_Float16)(atf.z * LOG2E), (_Float16)(atf.w * LOG2E)};
    const float4 bi = *reinterpret_cast<const float4*>(bias + u * 4);
    int e0 = rowstart[node];
    int e1 = rowend[node];

    float4 acc = {0, 0, 0, 0};
    float den = 0.0f;

    int e = e0;
    for (; e + 4 <= e1; e += 4) {
        int s0 = csr16[e + 0];
        int s1 = csr16[e + 1];
        int s2 = csr16[e + 2];
        int s3 = csr16[e + 3];
        uint2 r0 = *reinterpret_cast<const uint2*>(xl + (size_t)s0 * FDIM + u * 4);
        uint2 r1 = *reinterpret_cast<const uint2*>(xl + (size_t)s1 * FDIM + u * 4);
        uint2 r2 = *reinterpret_cast<const uint2*>(xl + (size_t)s2 * FDIM + u * 4);
        uint2 r3 = *reinterpret_cast<const uint2*>(xl + (size_t)s3 * FDIM + u * 4);
        gat_edge_step_h(xi0.v, xi1.v, a01, a23, r0, acc, den);
        gat_edge_step_h(xi0.v, xi1.v, a01, a23, r1, acc, den);
        gat_edge_step_h(xi0.v, xi1.v, a01, a23, r2, acc, den);
        gat_edge_step_h(xi0.v, xi1.v, a01, a23, r3, acc, den);
    }
    for (; e < e1; ++e) {
        int s0 = csr16[e];
        uint2 r0 = *reinterpret_cast<const uint2*>(xl + (size_t)s0 * FDIM + u * 4);
        gat_edge_step_h(xi0.v, xi1.v, a01, a23, r0, acc, den);
    }

    float inv = 1.0f / (den + 1e-16f);
    float4 o;
    o.x = acc.x * inv + bi.x;
    o.y = acc.y * inv + bi.y;
    o.z = acc.z * inv + bi.z;
    o.w = acc.w * inv + bi.w;
    *reinterpret_cast<float4*>(out + (size_t)node * FDIM + u * 4) = o;
}

extern "C" void kernel_launch(void* const* d_in, const int* in_sizes, int n_in,
                              void* d_out, int out_size, void* d_ws, size_t ws_size,
                              hipStream_t stream) {
    const float* x    = (const float*)d_in[0];
    const int*   ei   = (const int*)d_in[1];
    const float* Wl   = (const float*)d_in[2];
    const float* Wr   = (const float*)d_in[3];
    const float* att  = (const float*)d_in[4];
    const float* bias = (const float*)d_in[5];
    float* out = (float*)d_out;

    // ws layout (d_ws 256-aligned)
    __half* xl = (__half*)d_ws;                        // 12.8 MB
    __half* xr = xl + (size_t)NN * FDIM;               // 12.8 MB
    unsigned* binned = (unsigned*)(xr + (size_t)NN * FDIM); // NBUCK*BCAP u32 (4 MB)
    unsigned short* csr16 = (unsigned short*)(binned + (size_t)NBUCK * BCAP); // 2 MB
    int* rowstart  = (int*)(csr16 + (size_t)NBUCK * BCAP); // NN
    int* rowend    = rowstart + NN + 8;                // NN
    int* bcursor   = rowend + NN + 8;                  // NBUCK (counts)

    hipMemsetAsync(bcursor, 0, NBUCK * sizeof(int), stream);
    gat_fused_proj_bin<<<NCHUNK + PTILES, 512, 0, stream>>>(
        x, Wl, Wr, ei, bcursor, binned, xl, xr);
    gat_fine_pass<<<NBUCK, 512, 0, stream>>>(binned, bcursor, rowstart, rowend, csr16);
    gat_aggregate_kernel<<<(NN + 7) / 8, 256, 0, stream>>>(
        xl, xr, att, bias, rowstart, rowend, csr16, out);
}